// Round 10
// baseline (479.533 us; speedup 1.0000x reference)
//
#include <hip/hip_runtime.h>
#include <hip/hip_cooperative_groups.h>

namespace cg = cooperative_groups;

#define NN 50000
#define NE 800000
#define NB 196          // ceil(NN/256) node buckets of 256 nodes
#define NBLK 512        // edge chunks == cooperative grid size
#define CHUNK 1563      // ceil(NE/NBLK)
#define MAXB 6144       // max edges per bucket (mean 4081; +32 sigma)
// D = 128 features, HEADS=8, HID=16

typedef __bf16 bf16x8 __attribute__((ext_vector_type(8)));
typedef float  f32x4  __attribute__((ext_vector_type(4)));

__device__ __forceinline__ unsigned short f2bf(float x) {
    unsigned u = __float_as_uint(x);
    return (unsigned short)((u + 0x7FFFu + ((u >> 16) & 1u)) >> 16);   // RNE
}
__device__ __forceinline__ float bflo(unsigned u) { return __uint_as_float(u << 16); }
__device__ __forceinline__ float bfhi(unsigned u) { return __uint_as_float(u & 0xFFFF0000u); }

struct SortSM { int lcnt[256]; int sc[256]; int oat[256]; unsigned short outb[MAXB]; };

// ============ cooperative build: W-convert + hist + scan + scatter + bucket-sort ======
// 512 blocks x 256 threads (2 blocks/CU resident), phases separated by grid.sync().
__global__ __launch_bounds__(256, 2) void build_kernel(
    const float* __restrict__ Wa, const float* __restrict__ Wb,
    unsigned short* __restrict__ Wta, unsigned short* __restrict__ Wtb,
    const int* __restrict__ src1, const int* __restrict__ dst1,
    const int* __restrict__ src2, const int* __restrict__ dst2,
    int* __restrict__ histG, int* __restrict__ btot, int* __restrict__ bbase,
    unsigned int* __restrict__ bin1, unsigned int* __restrict__ bin2,
    unsigned short* __restrict__ csr1, int* __restrict__ start1, int* __restrict__ deg1,
    unsigned short* __restrict__ csr2, int* __restrict__ start2, int* __restrict__ deg2)
{
    __shared__ union {
        int h[2 * NB];
        int s[256];
        int pos[2 * NB];
        SortSM srt;
    } sm;
    cg::grid_group grid = cg::this_grid();
    const int t = threadIdx.x;
    const int blk = blockIdx.x;

    // ---- P0: per-chunk histogram over (graph,bucket); blocks 0,1 also convert W ----
    {
        for (int i = t; i < 2 * NB; i += 256) sm.h[i] = 0;
        __syncthreads();
        const int base = blk * CHUNK;
        const int lim = min(CHUNK, NE - base);
        for (int i = t; i < lim; i += 256) {
            atomicAdd(&sm.h[dst1[base + i] >> 8], 1);
            atomicAdd(&sm.h[NB + (dst2[base + i] >> 8)], 1);
        }
        __syncthreads();
        for (int i = t; i < 2 * NB; i += 256)
            histG[(size_t)i * NBLK + blk] = sm.h[i];
        if (blk < 2) {   // W transpose+convert (tiny; strided reads L2-absorbed)
            const float* W = blk ? Wb : Wa;
            unsigned short* Wt = blk ? Wtb : Wta;
            for (int j = t; j < 128 * 128; j += 256) {
                int n = j >> 7, k = j & 127;
                Wt[j] = f2bf(W[k * 128 + n]);
            }
        }
    }
    grid.sync();

    // ---- P1: exclusive scan of each (graph,bucket) row across 512 chunks ----
    if (blk < 2 * NB) {
        int* rowp = histG + (size_t)blk * NBLK;
        int v0 = rowp[2 * t], v1 = rowp[2 * t + 1];
        sm.s[t] = v0 + v1;
        __syncthreads();
        for (int off = 1; off < 256; off <<= 1) {
            int x = (t >= off) ? sm.s[t - off] : 0;
            __syncthreads();
            sm.s[t] += x;
            __syncthreads();
        }
        int incl = sm.s[t];
        int e0 = incl - (v0 + v1);
        rowp[2 * t] = e0;
        rowp[2 * t + 1] = e0 + v0;
        if (t == 255) btot[blk] = incl;
    }
    grid.sync();

    // ---- P2: exclusive scan of bucket totals per graph (block 0) ----
    if (blk == 0) {
        for (int g = 0; g < 2; g++) {
            int v = (t < NB) ? btot[g * NB + t] : 0;
            sm.s[t] = v;
            __syncthreads();
            for (int off = 1; off < 256; off <<= 1) {
                int x = (t >= off) ? sm.s[t - off] : 0;
                __syncthreads();
                sm.s[t] += x;
                __syncthreads();
            }
            if (t < NB) bbase[g * NB + t] = sm.s[t] - v;
            __syncthreads();
        }
    }
    grid.sync();

    // ---- P3: deterministic scatter into bucket-contiguous bins ----
    {
        for (int i = t; i < 2 * NB; i += 256)
            sm.pos[i] = bbase[i] + histG[(size_t)i * NBLK + blk];
        __syncthreads();
        const int base = blk * CHUNK;
        const int lim = min(CHUNK, NE - base);
        for (int i = t; i < lim; i += 256) {
            int d = dst1[base + i], s = src1[base + i];
            int slot = atomicAdd(&sm.pos[d >> 8], 1);
            bin1[slot] = ((unsigned)(d & 255) << 16) | (unsigned)s;
            d = dst2[base + i]; s = src2[base + i];
            slot = atomicAdd(&sm.pos[NB + (d >> 8)], 1);
            bin2[slot] = ((unsigned)(d & 255) << 16) | (unsigned)s;
        }
    }
    grid.sync();

    // ---- P4: per-bucket LDS counting sort, coalesced csr flush ----
    if (blk < 2 * NB) {
        const int g = (blk >= NB) ? 1 : 0;
        const int b = blk - g * NB;
        const unsigned int* bin = g ? bin2 : bin1;
        unsigned short* csr = g ? csr2 : csr1;
        int* start = g ? start2 : start1;
        int* deg   = g ? deg2 : deg1;
        const int base = bbase[g * NB + b];
        const int tot = min(btot[g * NB + b], MAXB);

        sm.srt.lcnt[t] = 0;
        __syncthreads();
        for (int i = t; i < tot; i += 256) atomicAdd(&sm.srt.lcnt[bin[base + i] >> 16], 1);
        __syncthreads();
        sm.srt.sc[t] = sm.srt.lcnt[t];
        __syncthreads();
        for (int off = 1; off < 256; off <<= 1) {
            int x = (t >= off) ? sm.srt.sc[t - off] : 0;
            __syncthreads();
            sm.srt.sc[t] += x;
            __syncthreads();
        }
        const int ex = sm.srt.sc[t] - sm.srt.lcnt[t];
        sm.srt.oat[t] = ex;
        __syncthreads();
        for (int i = t; i < tot; i += 256) {
            unsigned v = bin[base + i];
            int slot = atomicAdd(&sm.srt.oat[v >> 16], 1);
            sm.srt.outb[slot] = (unsigned short)(v & 0xFFFFu);
        }
        __syncthreads();
        for (int i = t; i < tot; i += 256) csr[base + i] = sm.srt.outb[i];
        int nd = b * 256 + t;
        if (nd < NN) { start[nd] = base + ex; deg[nd] = sm.srt.lcnt[t]; }
    }
}

// ---------------- MFMA GEMM (fp32 in): Y = X @ W + bias, X hi/lo split (2 MFMAs) ------
__global__ __launch_bounds__(256) void mfma_gemm_kernel(
    const float* __restrict__ X, const unsigned short* __restrict__ Wt,
    const float* __restrict__ bias, float* __restrict__ Y,
    unsigned short* __restrict__ Ybf, int nrows)
{
    __shared__ unsigned short Wl[128 * 128];   // 32 KB, granule-swizzled
    const int t = threadIdx.x;
    const int lane = t & 63;
    const int wv = t >> 6;
    const int row0 = blockIdx.x * 64;
    const int m16 = lane & 15;
    const int quad = lane >> 4;

    {
        const uint4* Wg = (const uint4*)Wt;
        #pragma unroll
        for (int i = 0; i < 8; i++) {
            int gi = t + i * 256;
            int n = gi >> 4, g = gi & 15;
            uint4 v = Wg[gi];
            *(uint4*)&Wl[n * 128 + (((g ^ (n & 15)) << 3))] = v;
        }
    }

    const int arow = row0 + wv * 16 + m16;
    const bool valid = (arow < nrows);
    const float4* X4 = (const float4*)X;
    float4 xr[8];
    #pragma unroll
    for (int kc = 0; kc < 4; kc++) {
        if (valid) {
            int gidx = arow * 32 + kc * 8 + quad * 2;
            xr[kc * 2]     = X4[gidx];
            xr[kc * 2 + 1] = X4[gidx + 1];
        } else {
            xr[kc * 2] = xr[kc * 2 + 1] = make_float4(0.f, 0.f, 0.f, 0.f);
        }
    }
    __syncthreads();

    f32x4 acc[8];
    #pragma unroll
    for (int nt = 0; nt < 8; nt++) acc[nt] = (f32x4){0.f, 0.f, 0.f, 0.f};

    #pragma unroll
    for (int kc = 0; kc < 4; kc++) {
        union { unsigned short u[8]; bf16x8 v; } ah, al;
        float f[8] = { xr[kc*2].x, xr[kc*2].y, xr[kc*2].z, xr[kc*2].w,
                       xr[kc*2+1].x, xr[kc*2+1].y, xr[kc*2+1].z, xr[kc*2+1].w };
        #pragma unroll
        for (int j = 0; j < 8; j++) {
            unsigned u = __float_as_uint(f[j]);
            ah.u[j] = (unsigned short)(u >> 16);
            al.u[j] = f2bf(f[j] - __uint_as_float(u & 0xFFFF0000u));
        }
        const int sgbase = (kc * 4 + quad);
        #pragma unroll
        for (int nt = 0; nt < 8; nt++) {
            const int n = nt * 16 + m16;
            bf16x8 b = *(const bf16x8*)&Wl[n * 128 + ((sgbase ^ m16) << 3)];
            acc[nt] = __builtin_amdgcn_mfma_f32_16x16x32_bf16(ah.v, b, acc[nt], 0, 0, 0);
            acc[nt] = __builtin_amdgcn_mfma_f32_16x16x32_bf16(al.v, b, acc[nt], 0, 0, 0);
        }
    }

    #pragma unroll
    for (int nt = 0; nt < 8; nt++) {
        const int col = nt * 16 + m16;
        const float bc = bias[col];
        #pragma unroll
        for (int r = 0; r < 4; r++) {
            int row = row0 + wv * 16 + quad * 4 + r;
            if (row < nrows) {
                float val = acc[nt][r] + bc;
                if (Y)   Y[(long)row * 128 + col] = val;
                if (Ybf) Ybf[(long)row * 128 + col] = f2bf(val);
            }
        }
    }
}

// ---------------- MFMA GEMM (bf16 in): Y = Xbf @ W + bias (1 MFMA per tile) -----------
__global__ __launch_bounds__(256) void mfma_gemm_bf16_kernel(
    const unsigned short* __restrict__ Xbf, const unsigned short* __restrict__ Wt,
    const float* __restrict__ bias, float* __restrict__ Y, int nrows)
{
    __shared__ unsigned short Wl[128 * 128];
    const int t = threadIdx.x;
    const int lane = t & 63;
    const int wv = t >> 6;
    const int row0 = blockIdx.x * 64;
    const int m16 = lane & 15;
    const int quad = lane >> 4;

    {
        const uint4* Wg = (const uint4*)Wt;
        #pragma unroll
        for (int i = 0; i < 8; i++) {
            int gi = t + i * 256;
            int n = gi >> 4, g = gi & 15;
            uint4 v = Wg[gi];
            *(uint4*)&Wl[n * 128 + (((g ^ (n & 15)) << 3))] = v;
        }
    }

    const int arow = row0 + wv * 16 + m16;
    const bool valid = (arow < nrows);
    const uint4* X16 = (const uint4*)Xbf;
    union { uint4 u; bf16x8 v; } xr[4];
    #pragma unroll
    for (int kc = 0; kc < 4; kc++) {
        if (valid) xr[kc].u = X16[arow * 16 + kc * 4 + quad];
        else       xr[kc].u = make_uint4(0, 0, 0, 0);
    }
    __syncthreads();

    f32x4 acc[8];
    #pragma unroll
    for (int nt = 0; nt < 8; nt++) acc[nt] = (f32x4){0.f, 0.f, 0.f, 0.f};

    #pragma unroll
    for (int kc = 0; kc < 4; kc++) {
        const int sgbase = (kc * 4 + quad);
        #pragma unroll
        for (int nt = 0; nt < 8; nt++) {
            const int n = nt * 16 + m16;
            bf16x8 b = *(const bf16x8*)&Wl[n * 128 + ((sgbase ^ m16) << 3)];
            acc[nt] = __builtin_amdgcn_mfma_f32_16x16x32_bf16(xr[kc].v, b, acc[nt], 0, 0, 0);
        }
    }

    #pragma unroll
    for (int nt = 0; nt < 8; nt++) {
        const int col = nt * 16 + m16;
        const float bc = bias[col];
        #pragma unroll
        for (int r = 0; r < 4; r++) {
            int row = row0 + wv * 16 + quad * 4 + r;
            if (row < nrows) Y[(long)row * 128 + col] = acc[nt][r] + bc;
        }
    }
}

// ---------------- fused gather + attention, half-wave edge pairing ---------------------
// Lanes 0-31 serve even edges, 32-63 odd edges; each lane loads uint2 (4 cols).
// Halves VMEM row-load instruction count vs 1-edge-per-wave-load.
__global__ __launch_bounds__(256) void gather_attn_kernel(
    const unsigned int* __restrict__ hfb,
    const unsigned short* __restrict__ csr1, const int* __restrict__ start1,
    const int* __restrict__ deg1, const float* __restrict__ norm1,
    const unsigned short* __restrict__ csr2, const int* __restrict__ start2,
    const int* __restrict__ deg2, const float* __restrict__ norm2,
    const float* __restrict__ al, const float* __restrict__ ar,
    unsigned int* __restrict__ outb)
{
    const int lane = threadIdx.x & 63;
    const int half = lane & 31;          // column-pair index within row
    const bool hi = (lane & 32) != 0;
    int node = (blockIdx.x * 256 + threadIdx.x) >> 6;
    if (node >= NN) return;
    node = __builtin_amdgcn_readfirstlane(node);

    float4 acc1 = make_float4(0.f, 0.f, 0.f, 0.f);
    float4 acc2 = make_float4(0.f, 0.f, 0.f, 0.f);

    #pragma unroll 1
    for (int g = 0; g < 2; g++) {
        const unsigned short* csr = g ? csr2 : csr1;
        const int* startp = g ? start2 : start1;
        const int* degp   = g ? deg2 : deg1;
        const float* norm = g ? norm2 : norm1;
        float4 acc = make_float4(0.f, 0.f, 0.f, 0.f);
        const int st = startp[node], dg = degp[node];
        for (int base = 0; base < dg; base += 64) {
            const int nb = min(64, dg - base);
            int myc = (lane < nb) ? (int)csr[st + base + lane] : 0;  // coalesced
            const int npairs = nb >> 1;
            int j = 0;
            for (; j + 4 <= npairs; j += 4) {
                float fn[4]; uint2 u[4];
                #pragma unroll
                for (int p = 0; p < 4; p++) {
                    int e = (j + p) * 2;
                    int s0 = __builtin_amdgcn_readlane(myc, e);
                    int s1 = __builtin_amdgcn_readlane(myc, e + 1);
                    float n0 = norm[s0], n1 = norm[s1];
                    int ss = hi ? s1 : s0;
                    fn[p] = hi ? n1 : n0;
                    u[p] = *(const uint2*)(hfb + ss * 64 + half * 2);
                }
                #pragma unroll
                for (int p = 0; p < 4; p++) {
                    acc.x = fmaf(bflo(u[p].x), fn[p], acc.x);
                    acc.y = fmaf(bfhi(u[p].x), fn[p], acc.y);
                    acc.z = fmaf(bflo(u[p].y), fn[p], acc.z);
                    acc.w = fmaf(bfhi(u[p].y), fn[p], acc.w);
                }
            }
            for (; j < npairs; j++) {
                int e = j * 2;
                int s0 = __builtin_amdgcn_readlane(myc, e);
                int s1 = __builtin_amdgcn_readlane(myc, e + 1);
                float n0 = norm[s0], n1 = norm[s1];
                int ss = hi ? s1 : s0;
                float fn = hi ? n1 : n0;
                uint2 u = *(const uint2*)(hfb + ss * 64 + half * 2);
                acc.x = fmaf(bflo(u.x), fn, acc.x);
                acc.y = fmaf(bfhi(u.x), fn, acc.y);
                acc.z = fmaf(bflo(u.y), fn, acc.z);
                acc.w = fmaf(bfhi(u.y), fn, acc.w);
            }
            if (nb & 1) {   // last unpaired edge: low half only
                int s0 = __builtin_amdgcn_readlane(myc, nb - 1);
                float fn = hi ? 0.f : norm[s0];
                uint2 u = *(const uint2*)(hfb + s0 * 64 + half * 2);
                acc.x = fmaf(bflo(u.x), fn, acc.x);
                acc.y = fmaf(bfhi(u.x), fn, acc.y);
                acc.z = fmaf(bflo(u.y), fn, acc.z);
                acc.w = fmaf(bfhi(u.y), fn, acc.w);
            }
        }
        // combine the two half-waves
        acc.x += __shfl_xor(acc.x, 32);
        acc.y += __shfl_xor(acc.y, 32);
        acc.z += __shfl_xor(acc.z, 32);
        acc.w += __shfl_xor(acc.w, 32);
        if (g) acc2 = acc; else acc1 = acc;
    }

    // h1 = acc1*norm1[node], h2 = acc2*norm2[node]
    const float nn1 = norm1[node], nn2 = norm2[node];
    acc1.x *= nn1; acc1.y *= nn1; acc1.z *= nn1; acc1.w *= nn1;
    acc2.x *= nn2; acc2.y *= nn2; acc2.z *= nn2; acc2.w *= nn2;

    // attention combine: lane half owns cols 4*half..4*half+3; chunk cc = half>>2 (4 lanes)
    const int cc = half >> 2;
    const int m = node * 8 + cc;
    const int head = m / NN;
    const int hid = (half & 3) * 4;
    uint2 uf = *(const uint2*)(hfb + node * 64 + half * 2);
    float4 f = make_float4(bflo(uf.x), bfhi(uf.x), bflo(uf.y), bfhi(uf.y));
    float4 av = *(const float4*)&al[head * 16 + hid];
    float4 rv = *(const float4*)&ar[head * 16 + hid];
    float s_ai = f.x * av.x + f.y * av.y + f.z * av.z + f.w * av.w;
    float s1 = acc1.x * rv.x + acc1.y * rv.y + acc1.z * rv.z + acc1.w * rv.w;
    float s2 = acc2.x * rv.x + acc2.y * rv.y + acc2.z * rv.z + acc2.w * rv.w;
    s_ai += __shfl_xor(s_ai, 1); s_ai += __shfl_xor(s_ai, 2);
    s1   += __shfl_xor(s1, 1);   s1   += __shfl_xor(s1, 2);
    s2   += __shfl_xor(s2, 1);   s2   += __shfl_xor(s2, 2);
    float x1 = s_ai + s1; x1 = x1 > 0.f ? x1 : 0.2f * x1;
    float x2 = s_ai + s2; x2 = x2 > 0.f ? x2 : 0.2f * x2;
    float e1 = fminf(expf(x1), 10.f);
    float e2 = fminf(expf(x2), 10.f);
    float inv = 1.f / (e1 + e2);
    float w1 = e1 * inv, w2 = e2 * inv;
    float o0 = w1 * acc1.x + w2 * acc2.x;
    float o1 = w1 * acc1.y + w2 * acc2.y;
    float o2 = w1 * acc1.z + w2 * acc2.z;
    float o3 = w1 * acc1.w + w2 * acc2.w;
    if (lane < 32) {
        unsigned p0 = (unsigned)f2bf(o0) | ((unsigned)f2bf(o1) << 16);
        unsigned p1 = (unsigned)f2bf(o2) | ((unsigned)f2bf(o3) << 16);
        ((uint2*)outb)[node * 32 + half] = make_uint2(p0, p1);
    }
}

extern "C" void kernel_launch(void* const* d_in, const int* in_sizes, int n_in,
                              void* d_out, int out_size, void* d_ws, size_t ws_size,
                              hipStream_t stream)
{
    const float* h     = (const float*)d_in[0];
    const int*   src1  = (const int*)  d_in[1];
    const int*   dst1  = (const int*)  d_in[2];
    const int*   src2  = (const int*)  d_in[3];
    const int*   dst2  = (const int*)  d_in[4];
    const float* norm1 = (const float*)d_in[5];
    const float* norm2 = (const float*)d_in[6];
    const float* W_lin = (const float*)d_in[7];
    const float* b_lin = (const float*)d_in[8];
    const float* al    = (const float*)d_in[9];
    const float* ar    = (const float*)d_in[10];
    const float* W_fc  = (const float*)d_in[11];
    const float* b_fc  = (const float*)d_in[12];
    float* out = (float*)d_out;

    // workspace layout
    unsigned short* hfb  = (unsigned short*)d_ws;         // NN*128 bf16 = 12.8 MB
    unsigned short* outbf = hfb + (size_t)NN * 128;       // NN*128 bf16 = 12.8 MB
    unsigned int* bin1 = (unsigned int*)(outbf + (size_t)NN * 128);  // NE u32
    unsigned int* bin2 = bin1 + NE;                       // NE u32
    unsigned short* csr1 = (unsigned short*)(bin2 + NE);  // NE u16
    unsigned short* csr2 = csr1 + NE;                     // NE u16
    unsigned short* WtL  = csr2 + NE;                     // 16384 u16
    unsigned short* WtF  = WtL + 128 * 128;               // 16384 u16
    int* histG  = (int*)(WtF + 128 * 128);                // 2*NB*NBLK ints
    int* btot   = histG + 2 * NB * NBLK;
    int* bbase  = btot + 2 * NB;
    int* start1 = bbase + 2 * NB;
    int* start2 = start1 + NN;
    int* deg1   = start2 + NN;
    int* deg2   = deg1 + NN;

    // 1) cooperative build: W-convert + full deterministic CSR construction
    {
        void* args[] = {
            (void*)&W_lin, (void*)&W_fc, (void*)&WtL, (void*)&WtF,
            (void*)&src1, (void*)&dst1, (void*)&src2, (void*)&dst2,
            (void*)&histG, (void*)&btot, (void*)&bbase,
            (void*)&bin1, (void*)&bin2,
            (void*)&csr1, (void*)&start1, (void*)&deg1,
            (void*)&csr2, (void*)&start2, (void*)&deg2
        };
        hipLaunchCooperativeKernel((void*)build_kernel, dim3(NBLK), dim3(256),
                                   args, 0, stream);
    }

    // 2) hfb = bf16(h @ W_lin + b_lin)
    mfma_gemm_kernel<<<(NN + 63) / 64, 256, 0, stream>>>(h, WtL, b_lin, nullptr, hfb, NN);

    // 3) fused gather (both graphs) + attention combine -> bf16
    gather_attn_kernel<<<(NN * 64) / 256, 256, 0, stream>>>(
        (const unsigned int*)hfb,
        csr1, start1, deg1, norm1,
        csr2, start2, deg2, norm2,
        al, ar, (unsigned int*)outbf);

    // 4) out = outbf @ W_fc + b_fc
    mfma_gemm_bf16_kernel<<<(NN + 63) / 64, 256, 0, stream>>>(outbf, WtF, b_fc, out, NN);
}

// Round 11
// 224.322 us; speedup vs baseline: 2.1377x; 2.1377x over previous
//
#include <hip/hip_runtime.h>

#define NN 50000
#define NE 800000
#define NB 196          // ceil(NN/256) node buckets of 256 nodes
#define NBG 392         // 2*NB (both graphs)
#define NBLK 128        // edge chunks
#define CHUNK 6250      // NE / NBLK exactly
#define MAXB 6144       // max edges per bucket (mean 4081; +32 sigma)
// D = 128 features, HEADS=8, HID=16

typedef __bf16 bf16x8 __attribute__((ext_vector_type(8)));
typedef float  f32x4  __attribute__((ext_vector_type(4)));

__device__ __forceinline__ unsigned short f2bf(float x) {
    unsigned u = __float_as_uint(x);
    return (unsigned short)((u + 0x7FFFu + ((u >> 16) & 1u)) >> 16);   // RNE
}
__device__ __forceinline__ float bflo(unsigned u) { return __uint_as_float(u << 16); }
__device__ __forceinline__ float bfhi(unsigned u) { return __uint_as_float(u & 0xFFFF0000u); }

// ---------------- phase A: per-chunk LDS histogram (chunk-major histG) + W convert ----
// blocks 0..127: histogram of chunk blk -> histG[blk*NBG + i]
// blocks 128,129: one-time W transpose+bf16 convert (independent work, stream-ordered
// before the GEMMs that consume it)
__global__ __launch_bounds__(1024) void histA_kernel(
    const int* __restrict__ dst1, const int* __restrict__ dst2, int* __restrict__ histG,
    const float* __restrict__ Wa, const float* __restrict__ Wb,
    unsigned short* __restrict__ Wta, unsigned short* __restrict__ Wtb)
{
    const int t = threadIdx.x, blk = blockIdx.x;
    if (blk >= NBLK) {   // W convert
        const float* W = (blk - NBLK) ? Wb : Wa;
        unsigned short* Wt = (blk - NBLK) ? Wtb : Wta;
        for (int j = t; j < 128 * 128; j += 1024) {
            int n = j >> 7, k = j & 127;
            Wt[j] = f2bf(W[k * 128 + n]);
        }
        return;
    }
    __shared__ int h[NBG];
    for (int i = t; i < NBG; i += 1024) h[i] = 0;
    __syncthreads();
    const int base = blk * CHUNK;
    for (int i = t; i < CHUNK; i += 1024) {
        atomicAdd(&h[dst1[base + i] >> 8], 1);
        atomicAdd(&h[NB + (dst2[base + i] >> 8)], 1);
    }
    __syncthreads();
    for (int i = t; i < NBG; i += 1024)
        histG[blk * NBG + i] = h[i];
}

// ---------------- phase C: scatter with LOCAL prefix computation (scans deleted) ------
// Each block recomputes bucket bases from histG (200 KB coalesced, L2-served).
// Block 0 publishes bbase/btot for bucket_sort.
__global__ __launch_bounds__(1024) void scatterC_kernel(
    const int* __restrict__ src1, const int* __restrict__ dst1,
    const int* __restrict__ src2, const int* __restrict__ dst2,
    const int* __restrict__ histG,
    int* __restrict__ gbbase, int* __restrict__ gbtot,
    unsigned int* __restrict__ bin1, unsigned int* __restrict__ bin2)
{
    __shared__ int s[512];
    __shared__ int pos[NBG];
    const int t = threadIdx.x, blk = blockIdx.x;

    int total_i = 0, pref_i = 0;
    if (t < NBG) {
        for (int c = 0; c < NBLK; c++) {
            int v = histG[c * NBG + t];          // coalesced across t
            total_i += v;
            if (c < blk) pref_i += v;
        }
    }
    if (t < 512) s[t] = (t < NBG) ? total_i : 0;
    __syncthreads();
    for (int off = 1; off < 512; off <<= 1) {
        int x = 0;
        if (t < 512 && t >= off) x = s[t - off];
        __syncthreads();
        if (t < 512) s[t] += x;
        __syncthreads();
    }
    const int sumG1 = s[NB - 1];   // inclusive over graph-1 buckets
    if (t < NBG) {
        int excl = s[t] - total_i;
        int bb = excl - ((t >= NB) ? sumG1 : 0);   // per-graph exclusive base
        pos[t] = bb + pref_i;
        if (blk == 0) { gbbase[t] = bb; gbtot[t] = total_i; }
    }
    __syncthreads();

    const int base = blk * CHUNK;
    for (int i = t; i < CHUNK; i += 1024) {
        int d = dst1[base + i], sv = src1[base + i];
        int slot = atomicAdd(&pos[d >> 8], 1);
        bin1[slot] = ((unsigned)(d & 255) << 16) | (unsigned)sv;
        d = dst2[base + i]; sv = src2[base + i];
        slot = atomicAdd(&pos[NB + (d >> 8)], 1);
        bin2[slot] = ((unsigned)(d & 255) << 16) | (unsigned)sv;
    }
}

// ---------------- bucket sort: LDS counting sort per bucket, coalesced csr flush ------
__global__ __launch_bounds__(256) void bucket_sort_kernel(
    const unsigned int* __restrict__ bin1, const unsigned int* __restrict__ bin2,
    const int* __restrict__ bbase, const int* __restrict__ btot,
    unsigned short* __restrict__ csr1, int* __restrict__ start1, int* __restrict__ deg1,
    unsigned short* __restrict__ csr2, int* __restrict__ start2, int* __restrict__ deg2)
{
    __shared__ int lcnt[256];
    __shared__ int sc[256];
    __shared__ int oat[256];
    __shared__ unsigned short outb[MAXB];
    const int t = threadIdx.x;
    const int g = (blockIdx.x >= NB) ? 1 : 0;
    const int b = blockIdx.x - g * NB;
    const unsigned int* bin = g ? bin2 : bin1;
    unsigned short* csr = g ? csr2 : csr1;
    int* start = g ? start2 : start1;
    int* deg   = g ? deg2 : deg1;

    const int base = bbase[g * NB + b];
    const int tot = min(btot[g * NB + b], MAXB);

    lcnt[t] = 0;
    __syncthreads();
    for (int i = t; i < tot; i += 256) atomicAdd(&lcnt[bin[base + i] >> 16], 1);
    __syncthreads();
    sc[t] = lcnt[t];
    __syncthreads();
    for (int off = 1; off < 256; off <<= 1) {
        int x = (t >= off) ? sc[t - off] : 0;
        __syncthreads();
        sc[t] += x;
        __syncthreads();
    }
    const int ex = sc[t] - lcnt[t];
    oat[t] = ex;
    __syncthreads();
    for (int i = t; i < tot; i += 256) {
        unsigned v = bin[base + i];
        int slot = atomicAdd(&oat[v >> 16], 1);
        outb[slot] = (unsigned short)(v & 0xFFFFu);
    }
    __syncthreads();
    for (int i = t; i < tot; i += 256) csr[base + i] = outb[i];
    int nd = b * 256 + t;
    if (nd < NN) { start[nd] = base + ex; deg[nd] = lcnt[t]; }
}

// ---------------- MFMA GEMM (fp32 in): Y = X @ W + bias, X hi/lo split (2 MFMAs) ------
__global__ __launch_bounds__(256) void mfma_gemm_kernel(
    const float* __restrict__ X, const unsigned short* __restrict__ Wt,
    const float* __restrict__ bias, float* __restrict__ Y,
    unsigned short* __restrict__ Ybf, int nrows)
{
    __shared__ unsigned short Wl[128 * 128];   // 32 KB, granule-swizzled
    const int t = threadIdx.x;
    const int lane = t & 63;
    const int wv = t >> 6;
    const int row0 = blockIdx.x * 64;
    const int m16 = lane & 15;
    const int quad = lane >> 4;

    {
        const uint4* Wg = (const uint4*)Wt;
        #pragma unroll
        for (int i = 0; i < 8; i++) {
            int gi = t + i * 256;
            int n = gi >> 4, g = gi & 15;
            uint4 v = Wg[gi];
            *(uint4*)&Wl[n * 128 + (((g ^ (n & 15)) << 3))] = v;
        }
    }

    const int arow = row0 + wv * 16 + m16;
    const bool valid = (arow < nrows);
    const float4* X4 = (const float4*)X;
    float4 xr[8];
    #pragma unroll
    for (int kc = 0; kc < 4; kc++) {
        if (valid) {
            int gidx = arow * 32 + kc * 8 + quad * 2;
            xr[kc * 2]     = X4[gidx];
            xr[kc * 2 + 1] = X4[gidx + 1];
        } else {
            xr[kc * 2] = xr[kc * 2 + 1] = make_float4(0.f, 0.f, 0.f, 0.f);
        }
    }
    __syncthreads();

    f32x4 acc[8];
    #pragma unroll
    for (int nt = 0; nt < 8; nt++) acc[nt] = (f32x4){0.f, 0.f, 0.f, 0.f};

    #pragma unroll
    for (int kc = 0; kc < 4; kc++) {
        union { unsigned short u[8]; bf16x8 v; } ah, al;
        float f[8] = { xr[kc*2].x, xr[kc*2].y, xr[kc*2].z, xr[kc*2].w,
                       xr[kc*2+1].x, xr[kc*2+1].y, xr[kc*2+1].z, xr[kc*2+1].w };
        #pragma unroll
        for (int j = 0; j < 8; j++) {
            unsigned u = __float_as_uint(f[j]);
            ah.u[j] = (unsigned short)(u >> 16);
            al.u[j] = f2bf(f[j] - __uint_as_float(u & 0xFFFF0000u));
        }
        const int sgbase = (kc * 4 + quad);
        #pragma unroll
        for (int nt = 0; nt < 8; nt++) {
            const int n = nt * 16 + m16;
            bf16x8 b = *(const bf16x8*)&Wl[n * 128 + ((sgbase ^ m16) << 3)];
            acc[nt] = __builtin_amdgcn_mfma_f32_16x16x32_bf16(ah.v, b, acc[nt], 0, 0, 0);
            acc[nt] = __builtin_amdgcn_mfma_f32_16x16x32_bf16(al.v, b, acc[nt], 0, 0, 0);
        }
    }

    #pragma unroll
    for (int nt = 0; nt < 8; nt++) {
        const int col = nt * 16 + m16;
        const float bc = bias[col];
        #pragma unroll
        for (int r = 0; r < 4; r++) {
            int row = row0 + wv * 16 + quad * 4 + r;
            if (row < nrows) {
                float val = acc[nt][r] + bc;
                if (Y)   Y[(long)row * 128 + col] = val;
                if (Ybf) Ybf[(long)row * 128 + col] = f2bf(val);
            }
        }
    }
}

// ---------------- MFMA GEMM (bf16 in): Y = Xbf @ W + bias (1 MFMA per tile) -----------
__global__ __launch_bounds__(256) void mfma_gemm_bf16_kernel(
    const unsigned short* __restrict__ Xbf, const unsigned short* __restrict__ Wt,
    const float* __restrict__ bias, float* __restrict__ Y, int nrows)
{
    __shared__ unsigned short Wl[128 * 128];
    const int t = threadIdx.x;
    const int lane = t & 63;
    const int wv = t >> 6;
    const int row0 = blockIdx.x * 64;
    const int m16 = lane & 15;
    const int quad = lane >> 4;

    {
        const uint4* Wg = (const uint4*)Wt;
        #pragma unroll
        for (int i = 0; i < 8; i++) {
            int gi = t + i * 256;
            int n = gi >> 4, g = gi & 15;
            uint4 v = Wg[gi];
            *(uint4*)&Wl[n * 128 + (((g ^ (n & 15)) << 3))] = v;
        }
    }

    const int arow = row0 + wv * 16 + m16;
    const bool valid = (arow < nrows);
    const uint4* X16 = (const uint4*)Xbf;
    union { uint4 u; bf16x8 v; } xr[4];
    #pragma unroll
    for (int kc = 0; kc < 4; kc++) {
        if (valid) xr[kc].u = X16[arow * 16 + kc * 4 + quad];
        else       xr[kc].u = make_uint4(0, 0, 0, 0);
    }
    __syncthreads();

    f32x4 acc[8];
    #pragma unroll
    for (int nt = 0; nt < 8; nt++) acc[nt] = (f32x4){0.f, 0.f, 0.f, 0.f};

    #pragma unroll
    for (int kc = 0; kc < 4; kc++) {
        const int sgbase = (kc * 4 + quad);
        #pragma unroll
        for (int nt = 0; nt < 8; nt++) {
            const int n = nt * 16 + m16;
            bf16x8 b = *(const bf16x8*)&Wl[n * 128 + ((sgbase ^ m16) << 3)];
            acc[nt] = __builtin_amdgcn_mfma_f32_16x16x32_bf16(xr[kc].v, b, acc[nt], 0, 0, 0);
        }
    }

    #pragma unroll
    for (int nt = 0; nt < 8; nt++) {
        const int col = nt * 16 + m16;
        const float bc = bias[col];
        #pragma unroll
        for (int r = 0; r < 4; r++) {
            int row = row0 + wv * 16 + quad * 4 + r;
            if (row < nrows) Y[(long)row * 128 + col] = acc[nt][r] + bc;
        }
    }
}

// ---------------- fused gather + attention: one wave per node, both graphs -------------
// (round-9 proven version: 8-deep pipeline, scalarized edge ids)
__global__ __launch_bounds__(256) void gather_attn_kernel(
    const unsigned int* __restrict__ hfb,
    const unsigned short* __restrict__ csr1, const int* __restrict__ start1,
    const int* __restrict__ deg1, const float* __restrict__ norm1,
    const unsigned short* __restrict__ csr2, const int* __restrict__ start2,
    const int* __restrict__ deg2, const float* __restrict__ norm2,
    const float* __restrict__ al, const float* __restrict__ ar,
    unsigned int* __restrict__ outb)
{
    const int lane = threadIdx.x & 63;
    int node = (blockIdx.x * 256 + threadIdx.x) >> 6;
    if (node >= NN) return;
    node = __builtin_amdgcn_readfirstlane(node);   // wave-uniform -> SGPR

    float2 acc1 = make_float2(0.f, 0.f), acc2 = make_float2(0.f, 0.f);

    #pragma unroll 1
    for (int g = 0; g < 2; g++) {
        const unsigned short* csr = g ? csr2 : csr1;
        const int* startp = g ? start2 : start1;
        const int* degp   = g ? deg2 : deg1;
        const float* norm = g ? norm2 : norm1;
        float2 acc = make_float2(0.f, 0.f);
        const int st = startp[node], dg = degp[node];
        for (int base = 0; base < dg; base += 64) {
            const int nb = min(64, dg - base);
            int myc = (lane < nb) ? (int)csr[st + base + lane] : 0;  // coalesced
            int j = 0;
            for (; j + 8 <= nb; j += 8) {
                int s[8]; float n[8]; unsigned u[8];
                #pragma unroll
                for (int q = 0; q < 8; q++) s[q] = __builtin_amdgcn_readlane(myc, j + q);
                #pragma unroll
                for (int q = 0; q < 8; q++) {
                    n[q] = norm[s[q]];
                    u[q] = hfb[(long)s[q] * 64 + lane];
                }
                #pragma unroll
                for (int q = 0; q < 8; q++) {
                    acc.x = fmaf(bflo(u[q]), n[q], acc.x);
                    acc.y = fmaf(bfhi(u[q]), n[q], acc.y);
                }
            }
            for (; j < nb; j++) {
                int s = __builtin_amdgcn_readlane(myc, j);
                float nv = norm[s];
                unsigned u = hfb[(long)s * 64 + lane];
                acc.x = fmaf(bflo(u), nv, acc.x);
                acc.y = fmaf(bfhi(u), nv, acc.y);
            }
        }
        if (g) acc2 = acc; else acc1 = acc;
    }

    const float nn1 = norm1[node], nn2 = norm2[node];
    acc1.x *= nn1; acc1.y *= nn1;
    acc2.x *= nn2; acc2.y *= nn2;

    // attention combine in flat-reshape space: lane owns cols {2*lane, 2*lane+1}
    const int cc = lane >> 3;
    const int m = node * 8 + cc;
    const int head = m / NN;
    const int hid = (2 * lane) & 15;
    unsigned uf = hfb[(long)node * 64 + lane];
    const float fx = bflo(uf), fy = bfhi(uf);
    const float av0 = al[head * 16 + hid], av1 = al[head * 16 + hid + 1];
    const float rv0 = ar[head * 16 + hid], rv1 = ar[head * 16 + hid + 1];
    float s_ai = fx * av0 + fy * av1;
    float s1 = acc1.x * rv0 + acc1.y * rv1;
    float s2 = acc2.x * rv0 + acc2.y * rv1;
    s_ai += __shfl_xor(s_ai, 1); s_ai += __shfl_xor(s_ai, 2); s_ai += __shfl_xor(s_ai, 4);
    s1   += __shfl_xor(s1, 1);   s1   += __shfl_xor(s1, 2);   s1   += __shfl_xor(s1, 4);
    s2   += __shfl_xor(s2, 1);   s2   += __shfl_xor(s2, 2);   s2   += __shfl_xor(s2, 4);
    float x1 = s_ai + s1; x1 = x1 > 0.f ? x1 : 0.2f * x1;
    float x2 = s_ai + s2; x2 = x2 > 0.f ? x2 : 0.2f * x2;
    float e1 = fminf(expf(x1), 10.f);
    float e2 = fminf(expf(x2), 10.f);
    float inv = 1.f / (e1 + e2);
    float w1 = e1 * inv, w2 = e2 * inv;
    float ox = w1 * acc1.x + w2 * acc2.x;
    float oy = w1 * acc1.y + w2 * acc2.y;
    outb[(long)node * 64 + lane] = (unsigned)f2bf(ox) | ((unsigned)f2bf(oy) << 16);
}

extern "C" void kernel_launch(void* const* d_in, const int* in_sizes, int n_in,
                              void* d_out, int out_size, void* d_ws, size_t ws_size,
                              hipStream_t stream)
{
    const float* h     = (const float*)d_in[0];
    const int*   src1  = (const int*)  d_in[1];
    const int*   dst1  = (const int*)  d_in[2];
    const int*   src2  = (const int*)  d_in[3];
    const int*   dst2  = (const int*)  d_in[4];
    const float* norm1 = (const float*)d_in[5];
    const float* norm2 = (const float*)d_in[6];
    const float* W_lin = (const float*)d_in[7];
    const float* b_lin = (const float*)d_in[8];
    const float* al    = (const float*)d_in[9];
    const float* ar    = (const float*)d_in[10];
    const float* W_fc  = (const float*)d_in[11];
    const float* b_fc  = (const float*)d_in[12];
    float* out = (float*)d_out;

    // workspace layout
    unsigned short* hfb  = (unsigned short*)d_ws;         // NN*128 bf16 = 12.8 MB
    unsigned short* outbf = hfb + (size_t)NN * 128;       // NN*128 bf16 = 12.8 MB
    unsigned int* bin1 = (unsigned int*)(outbf + (size_t)NN * 128);  // NE u32
    unsigned int* bin2 = bin1 + NE;                       // NE u32
    unsigned short* csr1 = (unsigned short*)(bin2 + NE);  // NE u16
    unsigned short* csr2 = csr1 + NE;                     // NE u16
    unsigned short* WtL  = csr2 + NE;                     // 16384 u16
    unsigned short* WtF  = WtL + 128 * 128;               // 16384 u16
    int* histG  = (int*)(WtF + 128 * 128);                // NBLK*NBG ints = 200 KB
    int* btot   = histG + NBLK * NBG;                     // 392
    int* bbase  = btot + NBG;                             // 392
    int* start1 = bbase + NBG;
    int* start2 = start1 + NN;
    int* deg1   = start2 + NN;
    int* deg2   = deg1 + NN;

    // 1) histogram (chunk-major) + one-time W bf16 conversion
    histA_kernel<<<NBLK + 2, 1024, 0, stream>>>(dst1, dst2, histG, W_lin, W_fc, WtL, WtF);

    // 2) hfb = bf16(h @ W_lin + b_lin)
    mfma_gemm_kernel<<<(NN + 63) / 64, 256, 0, stream>>>(h, WtL, b_lin, nullptr, hfb, NN);

    // 3) deterministic scatter (computes its own prefix sums; publishes bbase/btot)
    scatterC_kernel<<<NBLK, 1024, 0, stream>>>(src1, dst1, src2, dst2, histG,
                                               bbase, btot, bin1, bin2);

    // 4) per-bucket LDS counting sort -> u16 CSR + start/deg
    bucket_sort_kernel<<<NBG, 256, 0, stream>>>(bin1, bin2, bbase, btot,
                                                csr1, start1, deg1,
                                                csr2, start2, deg2);

    // 5) fused gather (both graphs) + attention combine -> bf16
    gather_attn_kernel<<<(NN * 64) / 256, 256, 0, stream>>>(
        (const unsigned int*)hfb,
        csr1, start1, deg1, norm1,
        csr2, start2, deg2, norm2,
        al, ar, (unsigned int*)outbf);

    // 6) out = outbf @ W_fc + b_fc
    mfma_gemm_bf16_kernel<<<(NN + 63) / 64, 256, 0, stream>>>(outbf, WtF, b_fc, out, NN);
}